// Round 1
// 715.970 us; speedup vs baseline: 1.0004x; 1.0004x over previous
//
#include <hip/hip_runtime.h>
#include <stdint.h>

#define NXR 8192      // rows of X / Gram
#define NQR 8192      // query rows
#define DMEAN 64
#define DVAR 96
#define DYC 32

typedef float f32x4 __attribute__((ext_vector_type(4)));
typedef __bf16 bf16x8 __attribute__((ext_vector_type(8)));
typedef unsigned short us4v __attribute__((ext_vector_type(4)));

__device__ __forceinline__ unsigned short f2bf(float f) {
    union { float f; uint32_t u; } v; v.f = f;
    uint32_t r = (v.u + 0x7FFFu + ((v.u >> 16) & 1u)) >> 16;
    return (unsigned short)r;
}
__device__ __forceinline__ float bf2f(unsigned short b) {
    union { uint32_t u; float f; } v; v.u = ((uint32_t)b) << 16;
    return v.f;
}
// frag-order permutation for a [K x 32] matrix used as MFMA B operand:
// element (k, c) -> kb*1024 + (c>>4)*512 + lane*8 + j,
// lane = ((k>>3)&3)*16 + (c&15), j = k&7
__device__ __forceinline__ int perm_idx(int k, int c) {
    return (k >> 5) * 1024 + (c >> 4) * 512 +
           ((((k >> 3) & 3) * 16 + (c & 15)) * 8) + (k & 7);
}

// ---------------- K1: prep (concat, flip, norms, bf16 casts, base out)
__global__ __launch_bounds__(256) void k_prep(
    const float* __restrict__ x_mu, const float* __restrict__ y_eta,
    const float* __restrict__ y_mean, const float* __restrict__ y_var,
    const float* __restrict__ X_mean, const float* __restrict__ X_var,
    const float* __restrict__ Z_mean, const float* __restrict__ Z_var,
    unsigned short* __restrict__ Qm, unsigned short* __restrict__ Qv,
    unsigned short* __restrict__ Xm, unsigned short* __restrict__ Xv,
    unsigned short* __restrict__ Zpm, unsigned short* __restrict__ Zpv,
    float* __restrict__ qn_m, float* __restrict__ qn_v,
    float* __restrict__ Xn_m, float* __restrict__ Xn_v,
    float* __restrict__ out)
{
    int w = threadIdx.x >> 6;
    int lane = threadIdx.x & 63;
    int row = blockIdx.x * 4 + w;

    float accq_m = 0.f, accq_v = 0.f;
    if (lane < 32) {
        int c = lane;
        float xm = x_mu[row * 32 + c];
        float s  = y_mean[row * 32 + c] + y_var[row * 32 + c];
        float e  = 0.01f * y_eta[(NQR - 1 - row) * 32 + c];
        unsigned short bx = f2bf(xm), bs = f2bf(s), be = f2bf(e);
        Qm[row * DMEAN + c] = bx;  Qm[row * DMEAN + 32 + c] = bs;
        Qv[row * DVAR + c] = bx;   Qv[row * DVAR + 32 + c] = be;
        Qv[row * DVAR + 64 + c] = bs;
        out[row * 32 + c] = s;     // base: y_mean + y_var
        Zpm[perm_idx(row, c)] = f2bf(Z_mean[row * 32 + c]);
        Zpv[perm_idx(row, c)] = f2bf(Z_var[row * 32 + c]);
        float fx = bf2f(bx), fs = bf2f(bs), fe = bf2f(be);
        accq_m = fx * fx + fs * fs;
        accq_v = fx * fx + fe * fe + fs * fs;
    }
    // X side: norms from bf16-rounded values for d2 consistency
    float a = X_mean[row * DMEAN + lane];
    unsigned short ba = f2bf(a);
    Xm[row * DMEAN + lane] = ba;
    float fa = bf2f(ba);
    float accx_m = fa * fa;

    float b0 = X_var[row * DVAR + lane];
    unsigned short bb0 = f2bf(b0);
    Xv[row * DVAR + lane] = bb0;
    float fb0 = bf2f(bb0);
    float accx_v = fb0 * fb0;
    if (lane < 32) {
        float b1 = X_var[row * DVAR + 64 + lane];
        unsigned short bb1 = f2bf(b1);
        Xv[row * DVAR + 64 + lane] = bb1;
        float fb1 = bf2f(bb1);
        accx_v += fb1 * fb1;
    }
    for (int o = 32; o >= 1; o >>= 1) {
        accq_m += __shfl_xor(accq_m, o, 64);
        accq_v += __shfl_xor(accq_v, o, 64);
        accx_m += __shfl_xor(accx_m, o, 64);
        accx_v += __shfl_xor(accx_v, o, 64);
    }
    if (lane == 0) {
        qn_m[row] = accq_m; qn_v[row] = accq_v;
        Xn_m[row] = accx_m; Xn_v[row] = accx_v;
    }
}

// ---------------- K2: Lambda = kXX_inv @ Z  (bf16 MFMA, deep-pipelined loads)
// Each block: 16 output rows x full K=8192. Wave w handles K-quarter w
// (64 k-blocks of 32), with a ping-pong register pipeline keeping 8 x dwordx4
// A-loads (8 KB/wave) in flight while the previous 4 k-blocks are processed.
// Cross-wave LDS reduction at the end; writes Lp directly in frag-order bf16
// (no split-K atomics, no fp32 intermediate, no pack kernel).
__global__ __launch_bounds__(256, 4) void k_lambda(
    const float* __restrict__ kXXm, const float* __restrict__ kXXv,
    const unsigned short* __restrict__ Zpm, const unsigned short* __restrict__ Zpv,
    unsigned short* __restrict__ Lpm, unsigned short* __restrict__ Lpv)
{
    __shared__ float red[4][64][8];
    int b = blockIdx.x;
    int mat = b & 1;
    int rg = b >> 1;                     // 0..511 row-group
    const float* A = mat ? kXXv : kXXm;
    const unsigned short* Zp = mat ? Zpv : Zpm;
    unsigned short* Lp = mat ? Lpv : Lpm;

    int w = threadIdx.x >> 6, lane = threadIdx.x & 63;
    int r0 = rg * 16;
    int arow = r0 + (lane & 15);
    int kgrp = (lane >> 4) * 8;
    const float* Arow = A + (size_t)arow * NXR;

    f32x4 acc0 = {0.f, 0.f, 0.f, 0.f}, acc1 = {0.f, 0.f, 0.f, 0.f};
    f32x4 bA[4][2], bB[4][2];
    int kb = w * 64;                     // this wave's K-quarter, 64 k-blocks

#define LOAD_BODY(BUF, KB0) do { \
    _Pragma("unroll") \
    for (int j = 0; j < 4; ++j) { \
        const f32x4* p = (const f32x4*)(Arow + (((KB0) + j) << 5) + kgrp); \
        BUF[j][0] = p[0]; BUF[j][1] = p[1]; \
    } } while (0)

#define PROC_BODY(BUF, KB0) do { \
    _Pragma("unroll") \
    for (int j = 0; j < 4; ++j) { \
        union { unsigned short u[8]; bf16x8 v; } af; \
        _Pragma("unroll") \
        for (int q2 = 0; q2 < 4; ++q2) { \
            af.u[q2] = f2bf(BUF[j][0][q2]); af.u[4 + q2] = f2bf(BUF[j][1][q2]); \
        } \
        const unsigned short* zb = Zp + (((size_t)((KB0) + j)) << 10) + lane * 8; \
        bf16x8 bz0 = *(const bf16x8*)(zb); \
        bf16x8 bz1 = *(const bf16x8*)(zb + 512); \
        acc0 = __builtin_amdgcn_mfma_f32_16x16x32_bf16(af.v, bz0, acc0, 0, 0, 0); \
        acc1 = __builtin_amdgcn_mfma_f32_16x16x32_bf16(af.v, bz1, acc1, 0, 0, 0); \
    } } while (0)

    LOAD_BODY(bA, kb);
#pragma unroll 1
    for (int s = 0; s < 7; ++s) {
        LOAD_BODY(bB, kb + 4);
        PROC_BODY(bA, kb);
        LOAD_BODY(bA, kb + 8);
        PROC_BODY(bB, kb + 4);
        kb += 8;
    }
    LOAD_BODY(bB, kb + 4);
    PROC_BODY(bA, kb);
    PROC_BODY(bB, kb + 4);
#undef LOAD_BODY
#undef PROC_BODY

    // cross-wave reduction over the 4 K-quarters
    *(f32x4*)&red[w][lane][0] = acc0;
    *(f32x4*)&red[w][lane][4] = acc1;
    __syncthreads();
    int t = threadIdx.x;
    int row = t >> 4, c16 = t & 15;           // row 0..15, col 0..15
    int ls = (row >> 2) * 16 + c16;           // source lane for (row, col)
    int rr = row & 3;                          // acc reg index
    float v0 = red[0][ls][rr] + red[1][ls][rr] + red[2][ls][rr] + red[3][ls][rr];
    float v1 = red[0][ls][4 + rr] + red[1][ls][4 + rr] +
               red[2][ls][4 + rr] + red[3][ls][4 + rr];
    Lp[perm_idx(r0 + row, c16)]      = f2bf(v0);
    Lp[perm_idx(r0 + row, c16 + 16)] = f2bf(v1);
}

// ---------------- K3: fused rbf + z = K^T @ Lambda (flash-style, no K matrix)
__global__ __launch_bounds__(256) void k_transport(
    const unsigned short* __restrict__ Qm, const unsigned short* __restrict__ Qv,
    const unsigned short* __restrict__ Xm, const unsigned short* __restrict__ Xv,
    const float* __restrict__ qn_m, const float* __restrict__ qn_v,
    const float* __restrict__ Xn_m, const float* __restrict__ Xn_v,
    const unsigned short* __restrict__ Lpm, const unsigned short* __restrict__ Lpv,
    float* __restrict__ out)
{
    __shared__ unsigned short KT[4][16 * 40];   // per-wave 16q x 32x tile, pitch 40
    int b = blockIdx.x;
    int mat = b & 1;
    int split = (b >> 1) & 3;
    int qb = b >> 3;                             // 0..127
    const unsigned short* Q = mat ? Qv : Qm;
    const unsigned short* X = mat ? Xv : Xm;
    const float* qn = mat ? qn_v : qn_m;
    const float* Xn = mat ? Xn_v : Xn_m;
    const unsigned short* Lp = mat ? Lpv : Lpm;
    const int D = mat ? DVAR : DMEAN;
    const int nk0 = mat ? 3 : 2;

    int w = threadIdx.x >> 6, lane = threadIdx.x & 63;
    int q0 = qb * 64 + w * 16;
    int qrow = q0 + (lane & 15);
    int g = lane >> 4;

    bf16x8 Qf[3];
    for (int c0 = 0; c0 < nk0; ++c0)
        Qf[c0] = *(const bf16x8*)(Q + (size_t)qrow * D + c0 * 32 + g * 8);
    float qn_c = qn[qrow];
    unsigned short* lds = KT[w];

    f32x4 z0 = {0.f, 0.f, 0.f, 0.f}, z1 = {0.f, 0.f, 0.f, 0.f};
    for (int xb = 0; xb < 64; ++xb) {
        int x0 = split * 2048 + xb * 32;
#pragma unroll
        for (int sub = 0; sub < 2; ++sub) {
            int xrow = x0 + sub * 16 + (lane & 15);
            const unsigned short* Xr = X + (size_t)xrow * D + g * 8;
            f32x4 s = {0.f, 0.f, 0.f, 0.f};
            s = __builtin_amdgcn_mfma_f32_16x16x32_bf16(*(const bf16x8*)(Xr), Qf[0], s, 0, 0, 0);
            s = __builtin_amdgcn_mfma_f32_16x16x32_bf16(*(const bf16x8*)(Xr + 32), Qf[1], s, 0, 0, 0);
            if (nk0 == 3)
                s = __builtin_amdgcn_mfma_f32_16x16x32_bf16(*(const bf16x8*)(Xr + 64), Qf[2], s, 0, 0, 0);
            int xnb = x0 + sub * 16 + g * 4;
            f32x4 xn4 = *(const f32x4*)(Xn + xnb);
            us4v kv;
#pragma unroll
            for (int r = 0; r < 4; ++r) {
                float d2 = xn4[r] + qn_c - 2.0f * s[r];
                d2 = fmaxf(d2, 0.0f);
                kv[r] = f2bf(__expf(-d2 * 0.0078125f));
            }
            // C-layout (col=q=lane&15, row=x_local) stored transposed: KT[q][x]
            *(us4v*)(lds + (lane & 15) * 40 + sub * 16 + g * 4) = kv;
        }
        // wave-private LDS: ensure the 64-lane writes completed before re-read
        asm volatile("s_waitcnt lgkmcnt(0)" ::: "memory");
        bf16x8 Kf = *(const bf16x8*)(lds + (lane & 15) * 40 + g * 8);  // A-frag KT[q][0..31]
        const unsigned short* lpb = Lp + (size_t)(x0 >> 5) * 1024 + lane * 8;
        bf16x8 l0 = *(const bf16x8*)(lpb);
        bf16x8 l1 = *(const bf16x8*)(lpb + 512);
        z0 = __builtin_amdgcn_mfma_f32_16x16x32_bf16(Kf, l0, z0, 0, 0, 0);
        z1 = __builtin_amdgcn_mfma_f32_16x16x32_bf16(Kf, l1, z1, 0, 0, 0);
    }
    int rbase = q0 + g * 4;
    int c0 = lane & 15;
#pragma unroll
    for (int r = 0; r < 4; ++r) {
        atomicAdd(&out[(rbase + r) * 32 + c0], z0[r]);
        atomicAdd(&out[(rbase + r) * 32 + c0 + 16], z1[r]);
    }
}

extern "C" void kernel_launch(void* const* d_in, const int* in_sizes, int n_in,
                              void* d_out, int out_size, void* d_ws, size_t ws_size,
                              hipStream_t stream) {
    const float* x_mu   = (const float*)d_in[0];
    const float* y_eta  = (const float*)d_in[1];
    const float* y_mean = (const float*)d_in[2];
    const float* y_var  = (const float*)d_in[3];
    const float* X_mean = (const float*)d_in[4];
    const float* X_var  = (const float*)d_in[5];
    const float* Z_mean = (const float*)d_in[6];
    const float* Z_var  = (const float*)d_in[7];
    const float* kXXm   = (const float*)d_in[8];
    const float* kXXv   = (const float*)d_in[9];
    float* out = (float*)d_out;

    char* ws = (char*)d_ws;
    size_t off = 0;
    auto carve = [&](size_t bytes) { char* p = ws + off; off += (bytes + 255) & ~(size_t)255; return p; };
    unsigned short* Qm  = (unsigned short*)carve(NQR * DMEAN * 2);
    unsigned short* Qv  = (unsigned short*)carve(NQR * DVAR * 2);
    unsigned short* Xm  = (unsigned short*)carve(NXR * DMEAN * 2);
    unsigned short* Xv  = (unsigned short*)carve(NXR * DVAR * 2);
    unsigned short* Zpm = (unsigned short*)carve(NXR * DYC * 2);
    unsigned short* Zpv = (unsigned short*)carve(NXR * DYC * 2);
    unsigned short* Lpm = (unsigned short*)carve(NXR * DYC * 2);
    unsigned short* Lpv = (unsigned short*)carve(NXR * DYC * 2);
    float* qn_m = (float*)carve(NQR * 4);
    float* qn_v = (float*)carve(NQR * 4);
    float* Xn_m = (float*)carve(NXR * 4);
    float* Xn_v = (float*)carve(NXR * 4);

    k_prep<<<dim3(2048), dim3(256), 0, stream>>>(
        x_mu, y_eta, y_mean, y_var, X_mean, X_var, Z_mean, Z_var,
        Qm, Qv, Xm, Xv, Zpm, Zpv, qn_m, qn_v, Xn_m, Xn_v, out);
    k_lambda<<<dim3(1024), dim3(256), 0, stream>>>(kXXm, kXXv, Zpm, Zpv, Lpm, Lpv);
    k_transport<<<dim3(1024), dim3(256), 0, stream>>>(
        Qm, Qv, Xm, Xv, qn_m, qn_v, Xn_m, Xn_v, Lpm, Lpv, out);
}

// Round 3
// 711.667 us; speedup vs baseline: 1.0065x; 1.0060x over previous
//
#include <hip/hip_runtime.h>
#include <stdint.h>

#define NXR 8192      // rows of X / Gram
#define NQR 8192      // query rows
#define DMEAN 64
#define DVAR 96
#define DYC 32

typedef float f32x4 __attribute__((ext_vector_type(4)));
typedef __bf16 bf16x8 __attribute__((ext_vector_type(8)));
typedef unsigned short us4v __attribute__((ext_vector_type(4)));

__device__ __forceinline__ unsigned short f2bf(float f) {
    union { float f; uint32_t u; } v; v.f = f;
    uint32_t r = (v.u + 0x7FFFu + ((v.u >> 16) & 1u)) >> 16;
    return (unsigned short)r;
}
__device__ __forceinline__ float bf2f(unsigned short b) {
    union { uint32_t u; float f; } v; v.u = ((uint32_t)b) << 16;
    return v.f;
}
// frag-order permutation for a [K x 32] matrix used as MFMA B operand:
// element (k, c) -> kb*1024 + (c>>4)*512 + lane*8 + j,
// lane = ((k>>3)&3)*16 + (c&15), j = k&7
__device__ __forceinline__ int perm_idx(int k, int c) {
    return (k >> 5) * 1024 + (c >> 4) * 512 +
           ((((k >> 3) & 3) * 16 + (c & 15)) * 8) + (k & 7);
}

// async global->LDS, 16B per lane (dest = wave-uniform base + lane*16)
typedef const __attribute__((address_space(1))) uint32_t* as1_u32p;
typedef __attribute__((address_space(3))) uint32_t* as3_u32p;
__device__ __forceinline__ void gl_lds16(const void* g, void* l) {
    __builtin_amdgcn_global_load_lds((as1_u32p)g, (as3_u32p)l, 16, 0, 0);
}

// ---------------- K1: prep (concat, flip, norms, bf16 casts, base out)
__global__ __launch_bounds__(256) void k_prep(
    const float* __restrict__ x_mu, const float* __restrict__ y_eta,
    const float* __restrict__ y_mean, const float* __restrict__ y_var,
    const float* __restrict__ X_mean, const float* __restrict__ X_var,
    const float* __restrict__ Z_mean, const float* __restrict__ Z_var,
    unsigned short* __restrict__ Qm, unsigned short* __restrict__ Qv,
    unsigned short* __restrict__ Xm, unsigned short* __restrict__ Xv,
    unsigned short* __restrict__ Zpm, unsigned short* __restrict__ Zpv,
    float* __restrict__ qn_m, float* __restrict__ qn_v,
    float* __restrict__ Xn_m, float* __restrict__ Xn_v,
    float* __restrict__ out)
{
    int w = threadIdx.x >> 6;
    int lane = threadIdx.x & 63;
    int row = blockIdx.x * 4 + w;

    float accq_m = 0.f, accq_v = 0.f;
    if (lane < 32) {
        int c = lane;
        float xm = x_mu[row * 32 + c];
        float s  = y_mean[row * 32 + c] + y_var[row * 32 + c];
        float e  = 0.01f * y_eta[(NQR - 1 - row) * 32 + c];
        unsigned short bx = f2bf(xm), bs = f2bf(s), be = f2bf(e);
        Qm[row * DMEAN + c] = bx;  Qm[row * DMEAN + 32 + c] = bs;
        Qv[row * DVAR + c] = bx;   Qv[row * DVAR + 32 + c] = be;
        Qv[row * DVAR + 64 + c] = bs;
        out[row * 32 + c] = s;     // base: y_mean + y_var
        Zpm[perm_idx(row, c)] = f2bf(Z_mean[row * 32 + c]);
        Zpv[perm_idx(row, c)] = f2bf(Z_var[row * 32 + c]);
        float fx = bf2f(bx), fs = bf2f(bs), fe = bf2f(be);
        accq_m = fx * fx + fs * fs;
        accq_v = fx * fx + fe * fe + fs * fs;
    }
    // X side: norms from bf16-rounded values for d2 consistency
    float a = X_mean[row * DMEAN + lane];
    unsigned short ba = f2bf(a);
    Xm[row * DMEAN + lane] = ba;
    float fa = bf2f(ba);
    float accx_m = fa * fa;

    float b0 = X_var[row * DVAR + lane];
    unsigned short bb0 = f2bf(b0);
    Xv[row * DVAR + lane] = bb0;
    float fb0 = bf2f(bb0);
    float accx_v = fb0 * fb0;
    if (lane < 32) {
        float b1 = X_var[row * DVAR + 64 + lane];
        unsigned short bb1 = f2bf(b1);
        Xv[row * DVAR + 64 + lane] = bb1;
        float fb1 = bf2f(bb1);
        accx_v += fb1 * fb1;
    }
    for (int o = 32; o >= 1; o >>= 1) {
        accq_m += __shfl_xor(accq_m, o, 64);
        accq_v += __shfl_xor(accq_v, o, 64);
        accx_m += __shfl_xor(accx_m, o, 64);
        accx_v += __shfl_xor(accx_v, o, 64);
    }
    if (lane == 0) {
        qn_m[row] = accq_m; qn_v[row] = accq_v;
        Xn_m[row] = accx_m; Xn_v[row] = accx_v;
    }
}

// ---------------- K2: Lambda = kXX_inv @ Z  (bf16 MFMA, global_load_lds pipeline)
// Block = 16 output rows x full K. Wave w owns K-quarter w (64 tiles of 32 cols),
// staging A (16x32 f32, XOR-swizzled source -> linear LDS) and Z (frag-order,
// identity) into wave-private LDS via global_load_lds.
// 2-deep schedule with 2 slots: only tiles t (waited) and t+1 (other slot) are
// ever in flight, so counted vmcnt(4) is race-free (3-deep with 2 slots raced:
// round-2 failure). No barrier, no register global loads in the K-loop.
__global__ __launch_bounds__(256, 4) void k_lambda(
    const float* __restrict__ kXXm, const float* __restrict__ kXXv,
    const unsigned short* __restrict__ Zpm, const unsigned short* __restrict__ Zpv,
    unsigned short* __restrict__ Lpm, unsigned short* __restrict__ Lpv)
{
    __shared__ __align__(16) char smem[32768];   // 4 waves x 2 slots x (2KB A + 2KB Z)
    int b = blockIdx.x;
    int mat = b & 1;
    int rg = b >> 1;                     // 0..511 row-group
    const float* A = mat ? kXXv : kXXm;
    const unsigned short* Zp = mat ? Zpv : Zpm;
    unsigned short* Lp = mat ? Lpv : Lpm;

    int w = threadIdx.x >> 6, lane = threadIdx.x & 63;
    int r0 = rg * 16;
    char* wb = smem + w * 8192;

    // staging source addresses (per lane)
    int rtA  = lane >> 3;                 // row within 8-row half (0..7)
    int srcA = ((lane & 7) * 16) ^ (rtA << 4);   // pre-swizzled col byte
    const char* A0 = (const char*)A + ((size_t)(r0 + rtA) * NXR) * 4
                     + (size_t)w * 8192 + srcA;          // + K-quarter offset
    const char* A1 = A0 + (size_t)8 * NXR * 4;           // rows +8
    const char* Zb = (const char*)Zp + (size_t)w * 64 * 2048 + lane * 16;

    // fragment read offsets (swizzled)
    int rt = lane & 15, g = lane >> 4;
    int ro0 = rt * 128 + (((g * 32) + 0)  ^ ((rt & 7) << 4));
    int ro1 = rt * 128 + (((g * 32) + 16) ^ ((rt & 7) << 4));

    f32x4 acc0 = {0.f, 0.f, 0.f, 0.f}, acc1 = {0.f, 0.f, 0.f, 0.f};

    auto stage = [&](int t) {
        char* base = wb + (t & 1) * 4096;
        size_t ko = (size_t)t * 128;                 // 32 floats per tile
        gl_lds16(A0 + ko, base);                     // A rows 0..7
        gl_lds16(A1 + ko, base + 1024);              // A rows 8..15
        gl_lds16(Zb + (size_t)t * 2048, base + 2048);        // Z frag lo
        gl_lds16(Zb + (size_t)t * 2048 + 1024, base + 3072); // Z frag hi
    };
    auto process = [&](int t) {
        char* base = wb + (t & 1) * 4096;
        f32x4 a0 = *(const f32x4*)(base + ro0);
        f32x4 a1 = *(const f32x4*)(base + ro1);
        bf16x8 bz0 = *(const bf16x8*)(base + 2048 + lane * 16);
        bf16x8 bz1 = *(const bf16x8*)(base + 3072 + lane * 16);
        union { unsigned short u[8]; bf16x8 v; } af;
#pragma unroll
        for (int j = 0; j < 4; ++j) { af.u[j] = f2bf(a0[j]); af.u[4 + j] = f2bf(a1[j]); }
        acc0 = __builtin_amdgcn_mfma_f32_16x16x32_bf16(af.v, bz0, acc0, 0, 0, 0);
        acc1 = __builtin_amdgcn_mfma_f32_16x16x32_bf16(af.v, bz1, acc1, 0, 0, 0);
    };

    stage(0);                            // 4 loads outstanding
#pragma unroll 1
    for (int t = 0; t < 63; ++t) {
        stage(t + 1);                    // 8 outstanding (tiles t, t+1 only)
        asm volatile("s_waitcnt vmcnt(4)" ::: "memory");  // tile t complete
        process(t);
    }
    asm volatile("s_waitcnt vmcnt(0)" ::: "memory");
    process(63);

    // cross-wave reduction over the 4 K-quarters (alias staging LDS)
    __syncthreads();
    float (*red)[64][8] = (float (*)[64][8])smem;
    *(f32x4*)&red[w][lane][0] = acc0;
    *(f32x4*)&red[w][lane][4] = acc1;
    __syncthreads();
    int tix = threadIdx.x;
    int row = tix >> 4, c16 = tix & 15;       // row 0..15, col 0..15
    int ls = (row >> 2) * 16 + c16;           // source lane for (row, col)
    int rr = row & 3;                          // acc reg index
    float v0 = red[0][ls][rr] + red[1][ls][rr] + red[2][ls][rr] + red[3][ls][rr];
    float v1 = red[0][ls][4 + rr] + red[1][ls][4 + rr] +
               red[2][ls][4 + rr] + red[3][ls][4 + rr];
    Lp[perm_idx(r0 + row, c16)]      = f2bf(v0);
    Lp[perm_idx(r0 + row, c16 + 16)] = f2bf(v1);
}

// ---------------- K3: fused rbf + z = K^T @ Lambda (flash-style, no K matrix)
__global__ __launch_bounds__(256) void k_transport(
    const unsigned short* __restrict__ Qm, const unsigned short* __restrict__ Qv,
    const unsigned short* __restrict__ Xm, const unsigned short* __restrict__ Xv,
    const float* __restrict__ qn_m, const float* __restrict__ qn_v,
    const float* __restrict__ Xn_m, const float* __restrict__ Xn_v,
    const unsigned short* __restrict__ Lpm, const unsigned short* __restrict__ Lpv,
    float* __restrict__ out)
{
    __shared__ unsigned short KT[4][16 * 40];   // per-wave 16q x 32x tile, pitch 40
    int b = blockIdx.x;
    int mat = b & 1;
    int split = (b >> 1) & 3;
    int qb = b >> 3;                             // 0..127
    const unsigned short* Q = mat ? Qv : Qm;
    const unsigned short* X = mat ? Xv : Xm;
    const float* qn = mat ? qn_v : qn_m;
    const float* Xn = mat ? Xn_v : Xn_m;
    const unsigned short* Lp = mat ? Lpv : Lpm;
    const int D = mat ? DVAR : DMEAN;
    const int nk0 = mat ? 3 : 2;

    int w = threadIdx.x >> 6, lane = threadIdx.x & 63;
    int q0 = qb * 64 + w * 16;
    int qrow = q0 + (lane & 15);
    int g = lane >> 4;

    bf16x8 Qf[3];
    for (int c0 = 0; c0 < nk0; ++c0)
        Qf[c0] = *(const bf16x8*)(Q + (size_t)qrow * D + c0 * 32 + g * 8);
    float qn_c = qn[qrow];
    unsigned short* lds = KT[w];

    f32x4 z0 = {0.f, 0.f, 0.f, 0.f}, z1 = {0.f, 0.f, 0.f, 0.f};
    for (int xb = 0; xb < 64; ++xb) {
        int x0 = split * 2048 + xb * 32;
#pragma unroll
        for (int sub = 0; sub < 2; ++sub) {
            int xrow = x0 + sub * 16 + (lane & 15);
            const unsigned short* Xr = X + (size_t)xrow * D + g * 8;
            f32x4 s = {0.f, 0.f, 0.f, 0.f};
            s = __builtin_amdgcn_mfma_f32_16x16x32_bf16(*(const bf16x8*)(Xr), Qf[0], s, 0, 0, 0);
            s = __builtin_amdgcn_mfma_f32_16x16x32_bf16(*(const bf16x8*)(Xr + 32), Qf[1], s, 0, 0, 0);
            if (nk0 == 3)
                s = __builtin_amdgcn_mfma_f32_16x16x32_bf16(*(const bf16x8*)(Xr + 64), Qf[2], s, 0, 0, 0);
            int xnb = x0 + sub * 16 + g * 4;
            f32x4 xn4 = *(const f32x4*)(Xn + xnb);
            us4v kv;
#pragma unroll
            for (int r = 0; r < 4; ++r) {
                float d2 = xn4[r] + qn_c - 2.0f * s[r];
                d2 = fmaxf(d2, 0.0f);
                kv[r] = f2bf(__expf(-d2 * 0.0078125f));
            }
            // C-layout (col=q=lane&15, row=x_local) stored transposed: KT[q][x]
            *(us4v*)(lds + (lane & 15) * 40 + sub * 16 + g * 4) = kv;
        }
        // wave-private LDS: ensure the 64-lane writes completed before re-read
        asm volatile("s_waitcnt lgkmcnt(0)" ::: "memory");
        bf16x8 Kf = *(const bf16x8*)(lds + (lane & 15) * 40 + g * 8);  // A-frag KT[q][0..31]
        const unsigned short* lpb = Lp + (size_t)(x0 >> 5) * 1024 + lane * 8;
        bf16x8 l0 = *(const bf16x8*)(lpb);
        bf16x8 l1 = *(const bf16x8*)(lpb + 512);
        z0 = __builtin_amdgcn_mfma_f32_16x16x32_bf16(Kf, l0, z0, 0, 0, 0);
        z1 = __builtin_amdgcn_mfma_f32_16x16x32_bf16(Kf, l1, z1, 0, 0, 0);
    }
    int rbase = q0 + g * 4;
    int c0 = lane & 15;
#pragma unroll
    for (int r = 0; r < 4; ++r) {
        atomicAdd(&out[(rbase + r) * 32 + c0], z0[r]);
        atomicAdd(&out[(rbase + r) * 32 + c0 + 16], z1[r]);
    }
}

extern "C" void kernel_launch(void* const* d_in, const int* in_sizes, int n_in,
                              void* d_out, int out_size, void* d_ws, size_t ws_size,
                              hipStream_t stream) {
    const float* x_mu   = (const float*)d_in[0];
    const float* y_eta  = (const float*)d_in[1];
    const float* y_mean = (const float*)d_in[2];
    const float* y_var  = (const float*)d_in[3];
    const float* X_mean = (const float*)d_in[4];
    const float* X_var  = (const float*)d_in[5];
    const float* Z_mean = (const float*)d_in[6];
    const float* Z_var  = (const float*)d_in[7];
    const float* kXXm   = (const float*)d_in[8];
    const float* kXXv   = (const float*)d_in[9];
    float* out = (float*)d_out;

    char* ws = (char*)d_ws;
    size_t off = 0;
    auto carve = [&](size_t bytes) { char* p = ws + off; off += (bytes + 255) & ~(size_t)255; return p; };
    unsigned short* Qm  = (unsigned short*)carve(NQR * DMEAN * 2);
    unsigned short* Qv  = (unsigned short*)carve(NQR * DVAR * 2);
    unsigned short* Xm  = (unsigned short*)carve(NXR * DMEAN * 2);
    unsigned short* Xv  = (unsigned short*)carve(NXR * DVAR * 2);
    unsigned short* Zpm = (unsigned short*)carve(NXR * DYC * 2);
    unsigned short* Zpv = (unsigned short*)carve(NXR * DYC * 2);
    unsigned short* Lpm = (unsigned short*)carve(NXR * DYC * 2);
    unsigned short* Lpv = (unsigned short*)carve(NXR * DYC * 2);
    float* qn_m = (float*)carve(NQR * 4);
    float* qn_v = (float*)carve(NQR * 4);
    float* Xn_m = (float*)carve(NXR * 4);
    float* Xn_v = (float*)carve(NXR * 4);

    k_prep<<<dim3(2048), dim3(256), 0, stream>>>(
        x_mu, y_eta, y_mean, y_var, X_mean, X_var, Z_mean, Z_var,
        Qm, Qv, Xm, Xv, Zpm, Zpv, qn_m, qn_v, Xn_m, Xn_v, out);
    k_lambda<<<dim3(1024), dim3(256), 0, stream>>>(kXXm, kXXv, Zpm, Zpv, Lpm, Lpv);
    k_transport<<<dim3(1024), dim3(256), 0, stream>>>(
        Qm, Qv, Xm, Xv, qn_m, qn_v, Xn_m, Xn_v, Lpm, Lpv, out);
}

// Round 4
// 687.419 us; speedup vs baseline: 1.0420x; 1.0353x over previous
//
#include <hip/hip_runtime.h>
#include <stdint.h>

#define NXR 8192      // rows of X / Gram
#define NQR 8192      // query rows
#define DMEAN 64
#define DVAR 96
#define DYC 32

typedef float f32x4 __attribute__((ext_vector_type(4)));
typedef __bf16 bf16x8 __attribute__((ext_vector_type(8)));
typedef unsigned short us4v __attribute__((ext_vector_type(4)));

__device__ __forceinline__ unsigned short f2bf(float f) {
    union { float f; uint32_t u; } v; v.f = f;
    uint32_t r = (v.u + 0x7FFFu + ((v.u >> 16) & 1u)) >> 16;
    return (unsigned short)r;
}
__device__ __forceinline__ float bf2f(unsigned short b) {
    union { uint32_t u; float f; } v; v.u = ((uint32_t)b) << 16;
    return v.f;
}
// frag-order permutation for a [K x 32] matrix used as MFMA B operand:
// element (k, c) -> kb*1024 + (c>>4)*512 + lane*8 + j,
// lane = ((k>>3)&3)*16 + (c&15), j = k&7
__device__ __forceinline__ int perm_idx(int k, int c) {
    return (k >> 5) * 1024 + (c >> 4) * 512 +
           ((((k >> 3) & 3) * 16 + (c & 15)) * 8) + (k & 7);
}

// async global->LDS, 16B per lane (dest = wave-uniform base; HW adds lane*16)
typedef const __attribute__((address_space(1))) uint32_t* as1_u32p;
typedef __attribute__((address_space(3))) uint32_t* as3_u32p;
__device__ __forceinline__ void gl_lds16(const void* g, void* l) {
    __builtin_amdgcn_global_load_lds((as1_u32p)g, (as3_u32p)l, 16, 0, 0);
}

// ---------------- K1: prep (concat, flip, norms, bf16 casts, base out)
__global__ __launch_bounds__(256) void k_prep(
    const float* __restrict__ x_mu, const float* __restrict__ y_eta,
    const float* __restrict__ y_mean, const float* __restrict__ y_var,
    const float* __restrict__ X_mean, const float* __restrict__ X_var,
    const float* __restrict__ Z_mean, const float* __restrict__ Z_var,
    unsigned short* __restrict__ Qm, unsigned short* __restrict__ Qv,
    unsigned short* __restrict__ Xm, unsigned short* __restrict__ Xv,
    unsigned short* __restrict__ Zpm, unsigned short* __restrict__ Zpv,
    float* __restrict__ qn_m, float* __restrict__ qn_v,
    float* __restrict__ Xn_m, float* __restrict__ Xn_v,
    float* __restrict__ out)
{
    int w = threadIdx.x >> 6;
    int lane = threadIdx.x & 63;
    int row = blockIdx.x * 4 + w;

    float accq_m = 0.f, accq_v = 0.f;
    if (lane < 32) {
        int c = lane;
        float xm = x_mu[row * 32 + c];
        float s  = y_mean[row * 32 + c] + y_var[row * 32 + c];
        float e  = 0.01f * y_eta[(NQR - 1 - row) * 32 + c];
        unsigned short bx = f2bf(xm), bs = f2bf(s), be = f2bf(e);
        Qm[row * DMEAN + c] = bx;  Qm[row * DMEAN + 32 + c] = bs;
        Qv[row * DVAR + c] = bx;   Qv[row * DVAR + 32 + c] = be;
        Qv[row * DVAR + 64 + c] = bs;
        out[row * 32 + c] = s;     // base: y_mean + y_var
        Zpm[perm_idx(row, c)] = f2bf(Z_mean[row * 32 + c]);
        Zpv[perm_idx(row, c)] = f2bf(Z_var[row * 32 + c]);
        float fx = bf2f(bx), fs = bf2f(bs), fe = bf2f(be);
        accq_m = fx * fx + fs * fs;
        accq_v = fx * fx + fe * fe + fs * fs;
    }
    // X side: norms from bf16-rounded values for d2 consistency
    float a = X_mean[row * DMEAN + lane];
    unsigned short ba = f2bf(a);
    Xm[row * DMEAN + lane] = ba;
    float fa = bf2f(ba);
    float accx_m = fa * fa;

    float b0 = X_var[row * DVAR + lane];
    unsigned short bb0 = f2bf(b0);
    Xv[row * DVAR + lane] = bb0;
    float fb0 = bf2f(bb0);
    float accx_v = fb0 * fb0;
    if (lane < 32) {
        float b1 = X_var[row * DVAR + 64 + lane];
        unsigned short bb1 = f2bf(b1);
        Xv[row * DVAR + 64 + lane] = bb1;
        float fb1 = bf2f(bb1);
        accx_v += fb1 * fb1;
    }
    for (int o = 32; o >= 1; o >>= 1) {
        accq_m += __shfl_xor(accq_m, o, 64);
        accq_v += __shfl_xor(accq_v, o, 64);
        accx_m += __shfl_xor(accx_m, o, 64);
        accx_v += __shfl_xor(accx_v, o, 64);
    }
    if (lane == 0) {
        qn_m[row] = accq_m; qn_v[row] = accq_v;
        Xn_m[row] = accx_m; Xn_v[row] = accx_v;
    }
}

// ---------------- K2: Lambda = kXX_inv @ Z  (contiguous super-tile streaming)
// Block = 16 rows x full K; wave w owns K-quarter w = 16 super-tiles of
// (16 rows x 512B). Each gl_lds16 reads 2 rows x 512B CONTIGUOUS (8 cache
// lines/row burst) -> HBM page-friendly, unlike the 128B-scatter of R0-R3.
// LDS [16][512B] with within-128B XOR row-swizzle (pre-swizzled source,
// linear dest, swizzled read). Z fragments double-buffered in registers
// (L2-hot). Depth-2 ring, stage-after-process: while proc(t) reads slot
// t&1, only tile t+1 (other slot) is in flight -> race-free. Counted
// vmcnt(16) waits (16 vmem ops per super-tile: 8 A-gl_lds + 8 Z-loads).
__global__ __launch_bounds__(256, 2) void k_lambda(
    const float* __restrict__ kXXm, const float* __restrict__ kXXv,
    const unsigned short* __restrict__ Zpm, const unsigned short* __restrict__ Zpv,
    unsigned short* __restrict__ Lpm, unsigned short* __restrict__ Lpv)
{
    __shared__ __align__(16) char smem[65536];   // 4 waves x 2 slots x 8KB
    int b = blockIdx.x;
    int mat = b & 1;
    int rg = b >> 1;                     // 0..511 row-group
    const float* A = mat ? kXXv : kXXm;
    const unsigned short* Zp = mat ? Zpv : Zpm;
    unsigned short* Lp = mat ? Lpv : Lpm;

    int w = threadIdx.x >> 6, lane = threadIdx.x & 63;
    int r0 = rg * 16;
    char* wlds = smem + w * 16384;

    // staging: instr i covers rows {2i, 2i+1}; lane loads 16B of row 2i+hl
    int hl = lane >> 5;                  // which row of the pair
    int cb = (lane & 31) * 16;           // byte col within the 512B row chunk
    const char* Ag = (const char*)A + (size_t)(r0 + hl) * 32768 + w * 8192;
    const char* Zq = (const char*)Zp + (size_t)w * 131072 + lane * 16;

    // fragment read offsets (swizzled), include wave LDS base
    int rt = lane & 15, g = lane >> 4;
    int sw = (rt & 7) << 4;
    int rd0 = w * 16384 + rt * 512 + ((g * 32) ^ sw);
    int rd1 = rd0 ^ 16;

    f32x4 acc0 = {0.f, 0.f, 0.f, 0.f}, acc1 = {0.f, 0.f, 0.f, 0.f};
    bf16x8 zA[8], zB[8];

    auto stageA = [&](int t, int slot) {
        char* d = wlds + slot;
        const char* s = Ag + (size_t)t * 512;
#pragma unroll
        for (int i = 0; i < 8; ++i) {
            int sw_i = ((2 * i + hl) & 7) << 4;
            gl_lds16(s + (size_t)i * 65536 + (cb ^ sw_i), d + i * 1024);
        }
    };
    auto loadZ = [&](bf16x8* z, int t) {
        const char* zb = Zq + (size_t)t * 8192;
#pragma unroll
        for (int kk = 0; kk < 4; ++kk) {
            z[2 * kk]     = *(const bf16x8*)(zb + kk * 2048);
            z[2 * kk + 1] = *(const bf16x8*)(zb + kk * 2048 + 1024);
        }
    };
    auto procST = [&](int slot, const bf16x8* z) {
#pragma unroll
        for (int kk = 0; kk < 4; ++kk) {
            f32x4 a0 = *(const f32x4*)(smem + rd0 + slot + kk * 128);
            f32x4 a1 = *(const f32x4*)(smem + rd1 + slot + kk * 128);
            union { unsigned short u[8]; bf16x8 v; } af;
#pragma unroll
            for (int j = 0; j < 4; ++j) { af.u[j] = f2bf(a0[j]); af.u[4 + j] = f2bf(a1[j]); }
            acc0 = __builtin_amdgcn_mfma_f32_16x16x32_bf16(af.v, z[2 * kk], acc0, 0, 0, 0);
            acc1 = __builtin_amdgcn_mfma_f32_16x16x32_bf16(af.v, z[2 * kk + 1], acc1, 0, 0, 0);
        }
    };

    stageA(0, 0);    loadZ(zA, 0);
    stageA(1, 8192); loadZ(zB, 1);
#pragma unroll 1
    for (int tt = 0; tt < 7; ++tt) {
        int t = 2 * tt;
        asm volatile("s_waitcnt vmcnt(16)" ::: "memory");   // tile t landed
        procST(0, zA);
        asm volatile("" ::: "memory");                      // reads before restage
        stageA(t + 2, 0);   loadZ(zA, t + 2);
        asm volatile("s_waitcnt vmcnt(16)" ::: "memory");   // tile t+1 landed
        procST(8192, zB);
        asm volatile("" ::: "memory");
        stageA(t + 3, 8192); loadZ(zB, t + 3);
    }
    asm volatile("s_waitcnt vmcnt(16)" ::: "memory");
    procST(0, zA);                                          // t = 14
    asm volatile("s_waitcnt vmcnt(0)" ::: "memory");
    procST(8192, zB);                                       // t = 15

    // cross-wave reduction over the 4 K-quarters (alias staging LDS)
    __syncthreads();
    float (*red)[64][8] = (float (*)[64][8])smem;
    *(f32x4*)&red[w][lane][0] = acc0;
    *(f32x4*)&red[w][lane][4] = acc1;
    __syncthreads();
    int tix = threadIdx.x;
    int row = tix >> 4, c16 = tix & 15;       // row 0..15, col 0..15
    int ls = (row >> 2) * 16 + c16;           // source lane for (row, col)
    int rr = row & 3;                          // acc reg index
    float v0 = red[0][ls][rr] + red[1][ls][rr] + red[2][ls][rr] + red[3][ls][rr];
    float v1 = red[0][ls][4 + rr] + red[1][ls][4 + rr] +
               red[2][ls][4 + rr] + red[3][ls][4 + rr];
    Lp[perm_idx(r0 + row, c16)]      = f2bf(v0);
    Lp[perm_idx(r0 + row, c16 + 16)] = f2bf(v1);
}

// ---------------- K3: fused rbf + z = K^T @ Lambda (flash-style, no K matrix)
__global__ __launch_bounds__(256) void k_transport(
    const unsigned short* __restrict__ Qm, const unsigned short* __restrict__ Qv,
    const unsigned short* __restrict__ Xm, const unsigned short* __restrict__ Xv,
    const float* __restrict__ qn_m, const float* __restrict__ qn_v,
    const float* __restrict__ Xn_m, const float* __restrict__ Xn_v,
    const unsigned short* __restrict__ Lpm, const unsigned short* __restrict__ Lpv,
    float* __restrict__ out)
{
    __shared__ unsigned short KT[4][16 * 40];   // per-wave 16q x 32x tile, pitch 40
    int b = blockIdx.x;
    int mat = b & 1;
    int split = (b >> 1) & 3;
    int qb = b >> 3;                             // 0..127
    const unsigned short* Q = mat ? Qv : Qm;
    const unsigned short* X = mat ? Xv : Xm;
    const float* qn = mat ? qn_v : qn_m;
    const float* Xn = mat ? Xn_v : Xn_m;
    const unsigned short* Lp = mat ? Lpv : Lpm;
    const int D = mat ? DVAR : DMEAN;
    const int nk0 = mat ? 3 : 2;

    int w = threadIdx.x >> 6, lane = threadIdx.x & 63;
    int q0 = qb * 64 + w * 16;
    int qrow = q0 + (lane & 15);
    int g = lane >> 4;

    bf16x8 Qf[3];
    for (int c0 = 0; c0 < nk0; ++c0)
        Qf[c0] = *(const bf16x8*)(Q + (size_t)qrow * D + c0 * 32 + g * 8);
    float qn_c = qn[qrow];
    unsigned short* lds = KT[w];

    f32x4 z0 = {0.f, 0.f, 0.f, 0.f}, z1 = {0.f, 0.f, 0.f, 0.f};
    for (int xb = 0; xb < 64; ++xb) {
        int x0 = split * 2048 + xb * 32;
#pragma unroll
        for (int sub = 0; sub < 2; ++sub) {
            int xrow = x0 + sub * 16 + (lane & 15);
            const unsigned short* Xr = X + (size_t)xrow * D + g * 8;
            f32x4 s = {0.f, 0.f, 0.f, 0.f};
            s = __builtin_amdgcn_mfma_f32_16x16x32_bf16(*(const bf16x8*)(Xr), Qf[0], s, 0, 0, 0);
            s = __builtin_amdgcn_mfma_f32_16x16x32_bf16(*(const bf16x8*)(Xr + 32), Qf[1], s, 0, 0, 0);
            if (nk0 == 3)
                s = __builtin_amdgcn_mfma_f32_16x16x32_bf16(*(const bf16x8*)(Xr + 64), Qf[2], s, 0, 0, 0);
            int xnb = x0 + sub * 16 + g * 4;
            f32x4 xn4 = *(const f32x4*)(Xn + xnb);
            us4v kv;
#pragma unroll
            for (int r = 0; r < 4; ++r) {
                float d2 = xn4[r] + qn_c - 2.0f * s[r];
                d2 = fmaxf(d2, 0.0f);
                kv[r] = f2bf(__expf(-d2 * 0.0078125f));
            }
            // C-layout (col=q=lane&15, row=x_local) stored transposed: KT[q][x]
            *(us4v*)(lds + (lane & 15) * 40 + sub * 16 + g * 4) = kv;
        }
        // wave-private LDS: ensure the 64-lane writes completed before re-read
        asm volatile("s_waitcnt lgkmcnt(0)" ::: "memory");
        bf16x8 Kf = *(const bf16x8*)(lds + (lane & 15) * 40 + g * 8);  // A-frag KT[q][0..31]
        const unsigned short* lpb = Lp + (size_t)(x0 >> 5) * 1024 + lane * 8;
        bf16x8 l0 = *(const bf16x8*)(lpb);
        bf16x8 l1 = *(const bf16x8*)(lpb + 512);
        z0 = __builtin_amdgcn_mfma_f32_16x16x32_bf16(Kf, l0, z0, 0, 0, 0);
        z1 = __builtin_amdgcn_mfma_f32_16x16x32_bf16(Kf, l1, z1, 0, 0, 0);
    }
    int rbase = q0 + g * 4;
    int c0 = lane & 15;
#pragma unroll
    for (int r = 0; r < 4; ++r) {
        atomicAdd(&out[(rbase + r) * 32 + c0], z0[r]);
        atomicAdd(&out[(rbase + r) * 32 + c0 + 16], z1[r]);
    }
}

extern "C" void kernel_launch(void* const* d_in, const int* in_sizes, int n_in,
                              void* d_out, int out_size, void* d_ws, size_t ws_size,
                              hipStream_t stream) {
    const float* x_mu   = (const float*)d_in[0];
    const float* y_eta  = (const float*)d_in[1];
    const float* y_mean = (const float*)d_in[2];
    const float* y_var  = (const float*)d_in[3];
    const float* X_mean = (const float*)d_in[4];
    const float* X_var  = (const float*)d_in[5];
    const float* Z_mean = (const float*)d_in[6];
    const float* Z_var  = (const float*)d_in[7];
    const float* kXXm   = (const float*)d_in[8];
    const float* kXXv   = (const float*)d_in[9];
    float* out = (float*)d_out;

    char* ws = (char*)d_ws;
    size_t off = 0;
    auto carve = [&](size_t bytes) { char* p = ws + off; off += (bytes + 255) & ~(size_t)255; return p; };
    unsigned short* Qm  = (unsigned short*)carve(NQR * DMEAN * 2);
    unsigned short* Qv  = (unsigned short*)carve(NQR * DVAR * 2);
    unsigned short* Xm  = (unsigned short*)carve(NXR * DMEAN * 2);
    unsigned short* Xv  = (unsigned short*)carve(NXR * DVAR * 2);
    unsigned short* Zpm = (unsigned short*)carve(NXR * DYC * 2);
    unsigned short* Zpv = (unsigned short*)carve(NXR * DYC * 2);
    unsigned short* Lpm = (unsigned short*)carve(NXR * DYC * 2);
    unsigned short* Lpv = (unsigned short*)carve(NXR * DYC * 2);
    float* qn_m = (float*)carve(NQR * 4);
    float* qn_v = (float*)carve(NQR * 4);
    float* Xn_m = (float*)carve(NXR * 4);
    float* Xn_v = (float*)carve(NXR * 4);

    k_prep<<<dim3(2048), dim3(256), 0, stream>>>(
        x_mu, y_eta, y_mean, y_var, X_mean, X_var, Z_mean, Z_var,
        Qm, Qv, Xm, Xv, Zpm, Zpv, qn_m, qn_v, Xn_m, Xn_v, out);
    k_lambda<<<dim3(1024), dim3(256), 0, stream>>>(kXXm, kXXv, Zpm, Zpv, Lpm, Lpv);
    k_transport<<<dim3(1024), dim3(256), 0, stream>>>(
        Qm, Qv, Xm, Xv, qn_m, qn_v, Xn_m, Xn_v, Lpm, Lpv, out);
}

// Round 5
// 679.863 us; speedup vs baseline: 1.0536x; 1.0111x over previous
//
#include <hip/hip_runtime.h>
#include <stdint.h>

#define NXR 8192      // rows of X / Gram
#define NQR 8192      // query rows
#define DMEAN 64
#define DVAR 96
#define DYC 32

typedef float f32x4 __attribute__((ext_vector_type(4)));
typedef __bf16 bf16x8 __attribute__((ext_vector_type(8)));
typedef unsigned short us4v __attribute__((ext_vector_type(4)));

__device__ __forceinline__ unsigned short f2bf(float f) {
    union { float f; uint32_t u; } v; v.f = f;
    uint32_t r = (v.u + 0x7FFFu + ((v.u >> 16) & 1u)) >> 16;
    return (unsigned short)r;
}
__device__ __forceinline__ float bf2f(unsigned short b) {
    union { uint32_t u; float f; } v; v.u = ((uint32_t)b) << 16;
    return v.f;
}
// frag-order permutation for a [K x 32] matrix used as MFMA B operand:
// element (k, c) -> kb*1024 + (c>>4)*512 + lane*8 + j,
// lane = ((k>>3)&3)*16 + (c&15), j = k&7
__device__ __forceinline__ int perm_idx(int k, int c) {
    return (k >> 5) * 1024 + (c >> 4) * 512 +
           ((((k >> 3) & 3) * 16 + (c & 15)) * 8) + (k & 7);
}

// async global->LDS, 16B per lane (dest = wave-uniform base; HW adds lane*16)
typedef const __attribute__((address_space(1))) uint32_t* as1_u32p;
typedef __attribute__((address_space(3))) uint32_t* as3_u32p;
__device__ __forceinline__ void gl_lds16(const void* g, void* l) {
    __builtin_amdgcn_global_load_lds((as1_u32p)g, (as3_u32p)l, 16, 0, 0);
}

// ---------------- K1: prep (concat, flip, norms, bf16 casts, base out)
__global__ __launch_bounds__(256) void k_prep(
    const float* __restrict__ x_mu, const float* __restrict__ y_eta,
    const float* __restrict__ y_mean, const float* __restrict__ y_var,
    const float* __restrict__ X_mean, const float* __restrict__ X_var,
    const float* __restrict__ Z_mean, const float* __restrict__ Z_var,
    unsigned short* __restrict__ Qm, unsigned short* __restrict__ Qv,
    unsigned short* __restrict__ Xm, unsigned short* __restrict__ Xv,
    unsigned short* __restrict__ Zpm, unsigned short* __restrict__ Zpv,
    float* __restrict__ qn_m, float* __restrict__ qn_v,
    float* __restrict__ Xn_m, float* __restrict__ Xn_v,
    float* __restrict__ out)
{
    int w = threadIdx.x >> 6;
    int lane = threadIdx.x & 63;
    int row = blockIdx.x * 4 + w;

    float accq_m = 0.f, accq_v = 0.f;
    if (lane < 32) {
        int c = lane;
        float xm = x_mu[row * 32 + c];
        float s  = y_mean[row * 32 + c] + y_var[row * 32 + c];
        float e  = 0.01f * y_eta[(NQR - 1 - row) * 32 + c];
        unsigned short bx = f2bf(xm), bs = f2bf(s), be = f2bf(e);
        Qm[row * DMEAN + c] = bx;  Qm[row * DMEAN + 32 + c] = bs;
        Qv[row * DVAR + c] = bx;   Qv[row * DVAR + 32 + c] = be;
        Qv[row * DVAR + 64 + c] = bs;
        out[row * 32 + c] = s;     // base: y_mean + y_var
        Zpm[perm_idx(row, c)] = f2bf(Z_mean[row * 32 + c]);
        Zpv[perm_idx(row, c)] = f2bf(Z_var[row * 32 + c]);
        float fx = bf2f(bx), fs = bf2f(bs), fe = bf2f(be);
        accq_m = fx * fx + fs * fs;
        accq_v = fx * fx + fe * fe + fs * fs;
    }
    // X side: norms from bf16-rounded values for d2 consistency
    float a = X_mean[row * DMEAN + lane];
    unsigned short ba = f2bf(a);
    Xm[row * DMEAN + lane] = ba;
    float fa = bf2f(ba);
    float accx_m = fa * fa;

    float b0 = X_var[row * DVAR + lane];
    unsigned short bb0 = f2bf(b0);
    Xv[row * DVAR + lane] = bb0;
    float fb0 = bf2f(bb0);
    float accx_v = fb0 * fb0;
    if (lane < 32) {
        float b1 = X_var[row * DVAR + 64 + lane];
        unsigned short bb1 = f2bf(b1);
        Xv[row * DVAR + 64 + lane] = bb1;
        float fb1 = bf2f(bb1);
        accx_v += fb1 * fb1;
    }
    for (int o = 32; o >= 1; o >>= 1) {
        accq_m += __shfl_xor(accq_m, o, 64);
        accq_v += __shfl_xor(accq_v, o, 64);
        accx_m += __shfl_xor(accx_m, o, 64);
        accx_v += __shfl_xor(accx_v, o, 64);
    }
    if (lane == 0) {
        qn_m[row] = accq_m; qn_v[row] = accq_v;
        Xn_m[row] = accx_m; Xn_v[row] = accx_v;
    }
}

// ---------------- K2: Lambda = kXX_inv @ Z  (contiguous super-tile streaming)
// (unchanged from round 4 — super-tile contiguous bursts, depth-2 ring)
__global__ __launch_bounds__(256, 2) void k_lambda(
    const float* __restrict__ kXXm, const float* __restrict__ kXXv,
    const unsigned short* __restrict__ Zpm, const unsigned short* __restrict__ Zpv,
    unsigned short* __restrict__ Lpm, unsigned short* __restrict__ Lpv)
{
    __shared__ __align__(16) char smem[65536];   // 4 waves x 2 slots x 8KB
    int b = blockIdx.x;
    int mat = b & 1;
    int rg = b >> 1;                     // 0..511 row-group
    const float* A = mat ? kXXv : kXXm;
    const unsigned short* Zp = mat ? Zpv : Zpm;
    unsigned short* Lp = mat ? Lpv : Lpm;

    int w = threadIdx.x >> 6, lane = threadIdx.x & 63;
    int r0 = rg * 16;
    char* wlds = smem + w * 16384;

    // staging: instr i covers rows {2i, 2i+1}; lane loads 16B of row 2i+hl
    int hl = lane >> 5;                  // which row of the pair
    int cb = (lane & 31) * 16;           // byte col within the 512B row chunk
    const char* Ag = (const char*)A + (size_t)(r0 + hl) * 32768 + w * 8192;
    const char* Zq = (const char*)Zp + (size_t)w * 131072 + lane * 16;

    // fragment read offsets (swizzled), include wave LDS base
    int rt = lane & 15, g = lane >> 4;
    int sw = (rt & 7) << 4;
    int rd0 = w * 16384 + rt * 512 + ((g * 32) ^ sw);
    int rd1 = rd0 ^ 16;

    f32x4 acc0 = {0.f, 0.f, 0.f, 0.f}, acc1 = {0.f, 0.f, 0.f, 0.f};
    bf16x8 zA[8], zB[8];

    auto stageA = [&](int t, int slot) {
        char* d = wlds + slot;
        const char* s = Ag + (size_t)t * 512;
#pragma unroll
        for (int i = 0; i < 8; ++i) {
            int sw_i = ((2 * i + hl) & 7) << 4;
            gl_lds16(s + (size_t)i * 65536 + (cb ^ sw_i), d + i * 1024);
        }
    };
    auto loadZ = [&](bf16x8* z, int t) {
        const char* zb = Zq + (size_t)t * 8192;
#pragma unroll
        for (int kk = 0; kk < 4; ++kk) {
            z[2 * kk]     = *(const bf16x8*)(zb + kk * 2048);
            z[2 * kk + 1] = *(const bf16x8*)(zb + kk * 2048 + 1024);
        }
    };
    auto procST = [&](int slot, const bf16x8* z) {
#pragma unroll
        for (int kk = 0; kk < 4; ++kk) {
            f32x4 a0 = *(const f32x4*)(smem + rd0 + slot + kk * 128);
            f32x4 a1 = *(const f32x4*)(smem + rd1 + slot + kk * 128);
            union { unsigned short u[8]; bf16x8 v; } af;
#pragma unroll
            for (int j = 0; j < 4; ++j) { af.u[j] = f2bf(a0[j]); af.u[4 + j] = f2bf(a1[j]); }
            acc0 = __builtin_amdgcn_mfma_f32_16x16x32_bf16(af.v, z[2 * kk], acc0, 0, 0, 0);
            acc1 = __builtin_amdgcn_mfma_f32_16x16x32_bf16(af.v, z[2 * kk + 1], acc1, 0, 0, 0);
        }
    };

    stageA(0, 0);    loadZ(zA, 0);
    stageA(1, 8192); loadZ(zB, 1);
#pragma unroll 1
    for (int tt = 0; tt < 7; ++tt) {
        int t = 2 * tt;
        asm volatile("s_waitcnt vmcnt(16)" ::: "memory");   // tile t landed
        procST(0, zA);
        asm volatile("" ::: "memory");                      // reads before restage
        stageA(t + 2, 0);   loadZ(zA, t + 2);
        asm volatile("s_waitcnt vmcnt(16)" ::: "memory");   // tile t+1 landed
        procST(8192, zB);
        asm volatile("" ::: "memory");
        stageA(t + 3, 8192); loadZ(zB, t + 3);
    }
    asm volatile("s_waitcnt vmcnt(16)" ::: "memory");
    procST(0, zA);                                          // t = 14
    asm volatile("s_waitcnt vmcnt(0)" ::: "memory");
    procST(8192, zB);                                       // t = 15

    // cross-wave reduction over the 4 K-quarters (alias staging LDS)
    __syncthreads();
    float (*red)[64][8] = (float (*)[64][8])smem;
    *(f32x4*)&red[w][lane][0] = acc0;
    *(f32x4*)&red[w][lane][4] = acc1;
    __syncthreads();
    int tix = threadIdx.x;
    int row = tix >> 4, c16 = tix & 15;       // row 0..15, col 0..15
    int ls = (row >> 2) * 16 + c16;           // source lane for (row, col)
    int rr = row & 3;                          // acc reg index
    float v0 = red[0][ls][rr] + red[1][ls][rr] + red[2][ls][rr] + red[3][ls][rr];
    float v1 = red[0][ls][4 + rr] + red[1][ls][4 + rr] +
               red[2][ls][4 + rr] + red[3][ls][4 + rr];
    Lp[perm_idx(r0 + row, c16)]      = f2bf(v0);
    Lp[perm_idx(r0 + row, c16 + 16)] = f2bf(v1);
}

// ---------------- K3: fused rbf + z = K^T @ Lambda (flash-style, pipelined)
// R4 diagnosis: every iteration issued its X/Lp/Xn loads cold behind a full
// memory fence -> two serialized ~500-700cy cache waits per 32-x iteration
// (MfmaUtil 7%, VALUBusy 28%, nothing else busy). Fix: A/B register sets with
// static indexing; prefetch tile t+1's X-frags/Lp/Xn BEFORE tile t's fence so
// latency hides under exp+LDS+PV of t and QK^T of t+1. Double LDS sub-buffer
// per wave removes the phase-to-phase WAR dependence.
__global__ __launch_bounds__(256, 3) void k_transport(
    const unsigned short* __restrict__ Qm, const unsigned short* __restrict__ Qv,
    const unsigned short* __restrict__ Xm, const unsigned short* __restrict__ Xv,
    const float* __restrict__ qn_m, const float* __restrict__ qn_v,
    const float* __restrict__ Xn_m, const float* __restrict__ Xn_v,
    const unsigned short* __restrict__ Lpm, const unsigned short* __restrict__ Lpv,
    float* __restrict__ out)
{
    __shared__ unsigned short KT[4][2][16 * 40];   // per-wave double 16q x 32x tile
    int b = blockIdx.x;
    int mat = b & 1;
    int split = (b >> 1) & 3;
    int qb = b >> 3;                             // 0..127
    const unsigned short* Q = mat ? Qv : Qm;
    const unsigned short* X = mat ? Xv : Xm;
    const float* qn = mat ? qn_v : qn_m;
    const float* Xn = mat ? Xn_v : Xn_m;
    const unsigned short* Lp = mat ? Lpv : Lpm;
    const int D = mat ? DVAR : DMEAN;
    const int nk0 = mat ? 3 : 2;

    int w = threadIdx.x >> 6, lane = threadIdx.x & 63;
    int q0 = qb * 64 + w * 16;
    int qrow = q0 + (lane & 15);
    int g = lane >> 4;

    bf16x8 Qf[3];
    for (int c0 = 0; c0 < nk0; ++c0)
        Qf[c0] = *(const bf16x8*)(Q + (size_t)qrow * D + c0 * 32 + g * 8);
    float qn_c = qn[qrow];

    f32x4 z0 = {0.f, 0.f, 0.f, 0.f}, z1 = {0.f, 0.f, 0.f, 0.f};

    // prefetch register sets (static indexing only)
    bf16x8 xA[6], xB[6];          // [sub*3 + frag]
    bf16x8 lpA[2], lpB[2];
    f32x4  xnA[2], xnB[2];

    auto loadX = [&](bf16x8* xf, int t) {
        int x0 = split * 2048 + (t & 63) * 32;
#pragma unroll
        for (int sub = 0; sub < 2; ++sub) {
            int xrow = x0 + sub * 16 + (lane & 15);
            const unsigned short* Xr = X + (size_t)xrow * D + g * 8;
            xf[sub * 3 + 0] = *(const bf16x8*)(Xr);
            xf[sub * 3 + 1] = *(const bf16x8*)(Xr + 32);
            if (nk0 == 3) xf[sub * 3 + 2] = *(const bf16x8*)(Xr + 64);
        }
    };
    auto loadAux = [&](bf16x8* lp, f32x4* xn, int t) {
        int x0 = split * 2048 + (t & 63) * 32;
        const unsigned short* lpb = Lp + (size_t)(x0 >> 5) * 1024 + lane * 8;
        lp[0] = *(const bf16x8*)(lpb);
        lp[1] = *(const bf16x8*)(lpb + 512);
        xn[0] = *(const f32x4*)(Xn + x0 + g * 4);
        xn[1] = *(const f32x4*)(Xn + x0 + 16 + g * 4);
    };
    auto phase = [&](const bf16x8* xf, const bf16x8* lp, const f32x4* xn,
                     unsigned short* lds) {
#pragma unroll
        for (int sub = 0; sub < 2; ++sub) {
            f32x4 s = {0.f, 0.f, 0.f, 0.f};
            s = __builtin_amdgcn_mfma_f32_16x16x32_bf16(xf[sub * 3 + 0], Qf[0], s, 0, 0, 0);
            s = __builtin_amdgcn_mfma_f32_16x16x32_bf16(xf[sub * 3 + 1], Qf[1], s, 0, 0, 0);
            if (nk0 == 3)
                s = __builtin_amdgcn_mfma_f32_16x16x32_bf16(xf[sub * 3 + 2], Qf[2], s, 0, 0, 0);
            us4v kv;
#pragma unroll
            for (int r = 0; r < 4; ++r) {
                float d2 = xn[sub][r] + qn_c - 2.0f * s[r];
                d2 = fmaxf(d2, 0.0f);
                kv[r] = f2bf(__expf(-d2 * 0.0078125f));
            }
            // C-layout (col=q=lane&15, row=x_local) stored transposed: KT[q][x]
            *(us4v*)(lds + (lane & 15) * 40 + sub * 16 + g * 4) = kv;
        }
        // wave-private LDS: ensure the 64-lane writes completed before re-read
        asm volatile("s_waitcnt lgkmcnt(0)" ::: "memory");
        bf16x8 Kf = *(const bf16x8*)(lds + (lane & 15) * 40 + g * 8);
        z0 = __builtin_amdgcn_mfma_f32_16x16x32_bf16(Kf, lp[0], z0, 0, 0, 0);
        z1 = __builtin_amdgcn_mfma_f32_16x16x32_bf16(Kf, lp[1], z1, 0, 0, 0);
    };

    loadX(xA, 0); loadAux(lpA, xnA, 0);
#pragma unroll 1
    for (int i = 0; i < 32; ++i) {
        int t = 2 * i;
        loadX(xB, t + 1); loadAux(lpB, xnB, t + 1);   // prefetch (in flight over phase A)
        phase(xA, lpA, xnA, KT[w][0]);
        loadX(xA, t + 2); loadAux(lpA, xnA, t + 2);   // prefetch (in flight over phase B)
        phase(xB, lpB, xnB, KT[w][1]);
    }

    int rbase = q0 + g * 4;
    int c0 = lane & 15;
#pragma unroll
    for (int r = 0; r < 4; ++r) {
        atomicAdd(&out[(rbase + r) * 32 + c0], z0[r]);
        atomicAdd(&out[(rbase + r) * 32 + c0 + 16], z1[r]);
    }
}

extern "C" void kernel_launch(void* const* d_in, const int* in_sizes, int n_in,
                              void* d_out, int out_size, void* d_ws, size_t ws_size,
                              hipStream_t stream) {
    const float* x_mu   = (const float*)d_in[0];
    const float* y_eta  = (const float*)d_in[1];
    const float* y_mean = (const float*)d_in[2];
    const float* y_var  = (const float*)d_in[3];
    const float* X_mean = (const float*)d_in[4];
    const float* X_var  = (const float*)d_in[5];
    const float* Z_mean = (const float*)d_in[6];
    const float* Z_var  = (const float*)d_in[7];
    const float* kXXm   = (const float*)d_in[8];
    const float* kXXv   = (const float*)d_in[9];
    float* out = (float*)d_out;

    char* ws = (char*)d_ws;
    size_t off = 0;
    auto carve = [&](size_t bytes) { char* p = ws + off; off += (bytes + 255) & ~(size_t)255; return p; };
    unsigned short* Qm  = (unsigned short*)carve(NQR * DMEAN * 2);
    unsigned short* Qv  = (unsigned short*)carve(NQR * DVAR * 2);
    unsigned short* Xm  = (unsigned short*)carve(NXR * DMEAN * 2);
    unsigned short* Xv  = (unsigned short*)carve(NXR * DVAR * 2);
    unsigned short* Zpm = (unsigned short*)carve(NXR * DYC * 2);
    unsigned short* Zpv = (unsigned short*)carve(NXR * DYC * 2);
    unsigned short* Lpm = (unsigned short*)carve(NXR * DYC * 2);
    unsigned short* Lpv = (unsigned short*)carve(NXR * DYC * 2);
    float* qn_m = (float*)carve(NQR * 4);
    float* qn_v = (float*)carve(NQR * 4);
    float* Xn_m = (float*)carve(NXR * 4);
    float* Xn_v = (float*)carve(NXR * 4);

    k_prep<<<dim3(2048), dim3(256), 0, stream>>>(
        x_mu, y_eta, y_mean, y_var, X_mean, X_var, Z_mean, Z_var,
        Qm, Qv, Xm, Xv, Zpm, Zpv, qn_m, qn_v, Xn_m, Xn_v, out);
    k_lambda<<<dim3(1024), dim3(256), 0, stream>>>(kXXm, kXXv, Zpm, Zpv, Lpm, Lpv);
    k_transport<<<dim3(1024), dim3(256), 0, stream>>>(
        Qm, Qv, Xm, Xv, qn_m, qn_v, Xn_m, Xn_v, Lpm, Lpv, out);
}